// Round 1
// baseline (2135.365 us; speedup 1.0000x reference)
//
#include <hip/hip_runtime.h>

// 2-layer bidirectional LSTM, B=256 T=2048 D=64, H1=16/dir, H2=8/dir.
// Layer-1: one wave per (batch, direction); lane = gate index (4*H1 = 64).
// Layer-2: one wave per batch; lanes 0-31 = fwd gates, 32-63 = bwd gates.
// All fp32 VALU. Scratch: out1 [B][T][32] fp32 = 67.1 MB at d_ws.

#ifndef __has_builtin
#define __has_builtin(x) 0
#endif

constexpr int Bn = 256;
constexpr int Tn = 2048;
constexpr int Dn = 64;
constexpr int H1n = 16;
constexpr int H2n = 8;

__device__ __forceinline__ float fast_rcp(float x) {
#if __has_builtin(__builtin_amdgcn_rcpf)
  return __builtin_amdgcn_rcpf(x);
#else
  return 1.0f / x;
#endif
}

// tanh(x) = 2*sigmoid(2x) - 1
__device__ __forceinline__ float tanh_fast(float x) {
  return fmaf(2.0f, fast_rcp(1.0f + __expf(-2.0f * x)), -1.0f);
}

// ---------------- Layer 1 ----------------
// grid = 512 (b*2 + dir), block = 64. Lane j owns gate row j of Wih1/Whh1.
__global__ __launch_bounds__(64) void l1_scan(
    const float* __restrict__ x,
    const float* __restrict__ wih_f, const float* __restrict__ whh_f,
    const float* __restrict__ bih_f, const float* __restrict__ bhh_f,
    const float* __restrict__ wih_b, const float* __restrict__ whh_b,
    const float* __restrict__ bih_b, const float* __restrict__ bhh_b,
    float* __restrict__ out1) {
  const int lane = threadIdx.x;          // 0..63 = gate index
  const int bid  = blockIdx.x;
  const int dir  = bid & 1;              // 0 fwd, 1 bwd
  const int b    = bid >> 1;

  const float* wih = dir ? wih_b : wih_f;   // [64][64]
  const float* whh = dir ? whh_b : whh_f;   // [64][16]
  const float* bih = dir ? bih_b : bih_f;
  const float* bhh = dir ? bhh_b : bhh_f;

  // Per-lane weight rows in registers.
  float wihr[Dn];
#pragma unroll
  for (int q = 0; q < Dn / 4; ++q) {
    float4 v = reinterpret_cast<const float4*>(wih + lane * Dn)[q];
    wihr[4 * q + 0] = v.x; wihr[4 * q + 1] = v.y;
    wihr[4 * q + 2] = v.z; wihr[4 * q + 3] = v.w;
  }
  float whhr[H1n];
#pragma unroll
  for (int q = 0; q < H1n / 4; ++q) {
    float4 v = reinterpret_cast<const float4*>(whh + lane * H1n)[q];
    whhr[4 * q + 0] = v.x; whhr[4 * q + 1] = v.y;
    whhr[4 * q + 2] = v.z; whhr[4 * q + 3] = v.w;
  }
  const float bias = bih[lane] + bhh[lane];

  const int k   = lane & 15;   // hidden unit
  const int grp = lane >> 4;   // 0:i 1:f 2:g(tanh) 3:o
  const float gin  = (grp == 2) ? 2.0f : 1.0f;   // input scale for tanh trick
  const float gout = (grp == 2) ? 2.0f : 1.0f;
  const float gsub = (grp == 2) ? -1.0f : 0.0f;

  __shared__ __align__(16) float xs[Dn];        // broadcast x row
  __shared__ __align__(16) float hs[H1n];       // broadcast h
  __shared__ __align__(16) float gs[H1n * 4];   // gates interleaved [k][ifgo]

  if (lane < H1n) hs[lane] = 0.0f;
  float c = 0.0f;

  const float* xb = x + (size_t)b * Tn * Dn;
  float* ob = out1 + (size_t)b * Tn * (2 * H1n) + dir * H1n;

  const int t0 = dir ? (Tn - 1) : 0;
  float xv = xb[(size_t)t0 * Dn + lane];   // prefetched x element

  for (int s = 0; s < Tn; ++s) {
    const int t  = dir ? (Tn - 1 - s) : s;
    const int sn = (s + 1 < Tn) ? (s + 1) : s;
    const int tn = dir ? (Tn - 1 - sn) : sn;

    xs[lane] = xv;
    float xvn = xb[(size_t)tn * Dn + lane];  // prefetch next step (hides HBM latency)
    __syncthreads();                          // (A) xs & hs visible

    float acc = bias;
    const float4* xs4 = reinterpret_cast<const float4*>(xs);
#pragma unroll
    for (int q = 0; q < Dn / 4; ++q) {
      float4 v = xs4[q];
      acc = fmaf(v.x, wihr[4 * q + 0], acc);
      acc = fmaf(v.y, wihr[4 * q + 1], acc);
      acc = fmaf(v.z, wihr[4 * q + 2], acc);
      acc = fmaf(v.w, wihr[4 * q + 3], acc);
    }
    const float4* hs4 = reinterpret_cast<const float4*>(hs);
#pragma unroll
    for (int q = 0; q < H1n / 4; ++q) {
      float4 v = hs4[q];
      acc = fmaf(v.x, whhr[4 * q + 0], acc);
      acc = fmaf(v.y, whhr[4 * q + 1], acc);
      acc = fmaf(v.z, whhr[4 * q + 2], acc);
      acc = fmaf(v.w, whhr[4 * q + 3], acc);
    }

    // one exp + one rcp per lane: sigmoid, or tanh via 2*sigmoid(2x)-1
    float sg  = fast_rcp(1.0f + __expf(-gin * acc));
    float val = fmaf(gout, sg, gsub);

    gs[k * 4 + grp] = val;
    __syncthreads();                          // (B) gates visible

    float4 g4 = reinterpret_cast<const float4*>(gs)[k];  // i,f,g,o
    c = fmaf(g4.y, c, g4.x * g4.z);
    const float h = g4.w * tanh_fast(c);

    if (lane < H1n) {
      hs[lane] = h;
      ob[(size_t)t * (2 * H1n) + lane] = h;
    }
    xv = xvn;
  }
}

// ---------------- Layer 2 ----------------
// grid = 256 (batch), block = 64. Lanes 0-31: fwd gates; 32-63: bwd gates.
__global__ __launch_bounds__(64) void l2_scan(
    const float* __restrict__ in,   // out1 [B][T][32]
    const float* __restrict__ wih_f, const float* __restrict__ whh_f,
    const float* __restrict__ bih_f, const float* __restrict__ bhh_f,
    const float* __restrict__ wih_b, const float* __restrict__ whh_b,
    const float* __restrict__ bib_b, const float* __restrict__ bhh_b,
    float* __restrict__ out) {      // [B][T][16]
  const int lane = threadIdx.x;
  const int half = lane >> 5;        // 0 fwd, 1 bwd
  const int j    = lane & 31;        // gate index within direction
  const int b    = blockIdx.x;

  const float* wih = half ? wih_b : wih_f;   // [32][32]
  const float* whh = half ? whh_b : whh_f;   // [32][8]
  const float* bih = half ? bib_b : bih_f;
  const float* bhh = half ? bhh_b : bhh_f;

  float wihr[2 * H1n];   // 32
#pragma unroll
  for (int q = 0; q < 8; ++q) {
    float4 v = reinterpret_cast<const float4*>(wih + j * 32)[q];
    wihr[4 * q + 0] = v.x; wihr[4 * q + 1] = v.y;
    wihr[4 * q + 2] = v.z; wihr[4 * q + 3] = v.w;
  }
  float whhr[H2n];       // 8
#pragma unroll
  for (int q = 0; q < 2; ++q) {
    float4 v = reinterpret_cast<const float4*>(whh + j * H2n)[q];
    whhr[4 * q + 0] = v.x; whhr[4 * q + 1] = v.y;
    whhr[4 * q + 2] = v.z; whhr[4 * q + 3] = v.w;
  }
  const float bias = bih[j] + bhh[j];

  const int k   = j & 7;    // hidden unit
  const int grp = j >> 3;   // 0:i 1:f 2:g 3:o
  const float gin  = (grp == 2) ? 2.0f : 1.0f;
  const float gout = (grp == 2) ? 2.0f : 1.0f;
  const float gsub = (grp == 2) ? -1.0f : 0.0f;

  __shared__ __align__(16) float xs[2][32];
  __shared__ __align__(16) float hs[2][H2n];
  __shared__ __align__(16) float gs[2][32];

  if (j < H2n) hs[half][j] = 0.0f;
  float c = 0.0f;

  const float* ib = in + (size_t)b * Tn * 32;
  float* ob = out + (size_t)b * Tn * 16 + half * H2n;

  const int t0 = half ? (Tn - 1) : 0;
  float xv = ib[(size_t)t0 * 32 + j];

  for (int s = 0; s < Tn; ++s) {
    const int t  = half ? (Tn - 1 - s) : s;
    const int sn = (s + 1 < Tn) ? (s + 1) : s;
    const int tn = half ? (Tn - 1 - sn) : sn;

    xs[half][j] = xv;
    float xvn = ib[(size_t)tn * 32 + j];
    __syncthreads();

    float acc = bias;
    const float4* xs4 = reinterpret_cast<const float4*>(xs[half]);
#pragma unroll
    for (int q = 0; q < 8; ++q) {
      float4 v = xs4[q];
      acc = fmaf(v.x, wihr[4 * q + 0], acc);
      acc = fmaf(v.y, wihr[4 * q + 1], acc);
      acc = fmaf(v.z, wihr[4 * q + 2], acc);
      acc = fmaf(v.w, wihr[4 * q + 3], acc);
    }
    const float4* hs4 = reinterpret_cast<const float4*>(hs[half]);
#pragma unroll
    for (int q = 0; q < 2; ++q) {
      float4 v = hs4[q];
      acc = fmaf(v.x, whhr[4 * q + 0], acc);
      acc = fmaf(v.y, whhr[4 * q + 1], acc);
      acc = fmaf(v.z, whhr[4 * q + 2], acc);
      acc = fmaf(v.w, whhr[4 * q + 3], acc);
    }

    float sg  = fast_rcp(1.0f + __expf(-gin * acc));
    float val = fmaf(gout, sg, gsub);

    gs[half][k * 4 + grp] = val;
    __syncthreads();

    float4 g4 = reinterpret_cast<const float4*>(gs[half])[k];
    c = fmaf(g4.y, c, g4.x * g4.z);
    const float h = g4.w * tanh_fast(c);

    if (j < H2n) {
      hs[half][j] = h;
      ob[(size_t)t * 16 + j] = h;
    }
    xv = xvn;
  }
}

extern "C" void kernel_launch(void* const* d_in, const int* in_sizes, int n_in,
                              void* d_out, int out_size, void* d_ws, size_t ws_size,
                              hipStream_t stream) {
  const float* x     = (const float*)d_in[0];
  const float* wih1f = (const float*)d_in[1];
  const float* whh1f = (const float*)d_in[2];
  const float* bih1f = (const float*)d_in[3];
  const float* bhh1f = (const float*)d_in[4];
  const float* wih1b = (const float*)d_in[5];
  const float* whh1b = (const float*)d_in[6];
  const float* bih1b = (const float*)d_in[7];
  const float* bhh1b = (const float*)d_in[8];
  const float* wih2f = (const float*)d_in[9];
  const float* whh2f = (const float*)d_in[10];
  const float* bih2f = (const float*)d_in[11];
  const float* bhh2f = (const float*)d_in[12];
  const float* wih2b = (const float*)d_in[13];
  const float* whh2b = (const float*)d_in[14];
  const float* bih2b = (const float*)d_in[15];
  const float* bhh2b = (const float*)d_in[16];

  float* out1 = (float*)d_ws;                 // [B][T][32] fp32 = 67.1 MB
  float* out  = (float*)d_out;                // [B][T][16] fp32

  l1_scan<<<Bn * 2, 64, 0, stream>>>(x, wih1f, whh1f, bih1f, bhh1f,
                                     wih1b, whh1b, bih1b, bhh1b, out1);
  l2_scan<<<Bn, 64, 0, stream>>>(out1, wih2f, whh2f, bih2f, bhh2f,
                                 wih2b, whh2b, bih2b, bhh2b, out);
}